// Round 8
// baseline (93.679 us; speedup 1.0000x reference)
//
#include <hip/hip_runtime.h>

typedef unsigned long long u64;
typedef unsigned int u32;
typedef unsigned short u16;

#define D_FEAT 32
#define NPB 128            // nodes per bucket
#define BSHIFT 7           // log2(NPB)
#define NB_MAX 1024        // max bucket count supported by scan / LDS arrays
#define NBLK 512           // edge-chunk blocks for count/scatter
#define ABLK 512           // threads per block for count/scatter
#define CAP 4096           // edges per LDS chunk in sort_gather
#define PAD 16             // pad global bucket counters to 64 B

// ---------- K1: fused count + reserve ----------
__global__ void __launch_bounds__(ABLK)
count_reserve(const int* __restrict__ ei, int* __restrict__ btot,
              int* __restrict__ rel, int E, int NB, int epb) {
    __shared__ int hist[NB_MAX];
    for (int k = threadIdx.x; k < NB; k += blockDim.x) hist[k] = 0;
    __syncthreads();
    const int e0 = blockIdx.x * epb;
    const int e1 = min(E, e0 + epb);
    for (int e = e0 + threadIdx.x; e < e1; e += blockDim.x)
        atomicAdd(&hist[ei[e] >> BSHIFT], 1);
    __syncthreads();
    for (int k = threadIdx.x; k < NB; k += blockDim.x) {
        const int h = hist[k];
        rel[(size_t)blockIdx.x * NB + k] = h ? atomicAdd(&btot[k * PAD], h) : 0;
    }
}

// ---------- K2: exclusive scan of bucket totals (one block) ----------
__global__ void __launch_bounds__(NB_MAX)
scan_totals(const int* __restrict__ btot, int* __restrict__ bbase, int NB) {
    __shared__ int lds[NB_MAX];
    const int t = threadIdx.x;
    const int v = (t < NB) ? btot[t * PAD] : 0;
    lds[t] = v;
    __syncthreads();
    for (int d = 1; d < NB_MAX; d <<= 1) {
        int tmp = (t >= d) ? lds[t - d] : 0;
        __syncthreads();
        lds[t] += tmp;
        __syncthreads();
    }
    if (t < NB) bbase[t] = lds[t] - v;
    if (t == NB - 1) bbase[NB] = lds[t];    // total = E
}

// ---------- K3: scatter edges into bucket-contiguous slots, LDS cursors ----------
__global__ void __launch_bounds__(ABLK)
bin_scatter(const int* __restrict__ ei, const float* __restrict__ attr,
            const int* __restrict__ rel, const int* __restrict__ bbase,
            u64* __restrict__ dstbuf, int E, int NB, int epb) {
    __shared__ int cur[NB_MAX];
    for (int k = threadIdx.x; k < NB; k += blockDim.x)
        cur[k] = bbase[k] + rel[(size_t)blockIdx.x * NB + k];
    __syncthreads();
    const int e0 = blockIdx.x * epb;
    const int e1 = min(E, e0 + epb);
    for (int e = e0 + threadIdx.x; e < e1; e += blockDim.x) {
        const int s = ei[e];
        const u32 d = (u32)ei[E + e];
        const u32 a = __float_as_uint(attr[e]);
        const int pos = atomicAdd(&cur[s >> BSHIFT], 1);
        const u32 lo = d | ((u32)(s & (NPB - 1)) << 20);  // dst(20b) | local_src(7b)
        dstbuf[pos] = ((u64)a << 32) | lo;
    }
}

// ---------- K4: fused per-bucket sort + gather ----------
// One 512-thread block per bucket. Stage edges in LDS, index-sort by local
// node, then 8 lanes/node walk the segment and accumulate in registers.
// Chunked over CAP for generality; accumulators persist across chunks.
__global__ void __launch_bounds__(512)
sort_gather(const u64* __restrict__ srcbuf, const int* __restrict__ bbase,
            const float* __restrict__ x, float* __restrict__ out, int N) {
    __shared__ u64 stage[CAP];      // 32 KB
    __shared__ u16 idx[CAP];        // 8 KB
    __shared__ int hist[NPB];       // inclusive prefix after scan
    __shared__ int cur[NPB];
    const int k = blockIdx.x, t = threadIdx.x;
    const int start = bbase[k], end = bbase[k + 1];

    const int g0 = t >> 3;          // node group 0..63 (owns g0 and g0+64)
    const int l4 = (t & 7) << 2;    // feature*4

    float4 acc0 = {0.f, 0.f, 0.f, 0.f};
    float4 acc1 = {0.f, 0.f, 0.f, 0.f};

    for (int cbase = start; cbase < end; cbase += CAP) {
        const int cnt = min(CAP, end - cbase);

        __syncthreads();                 // prior chunk's LDS reads done
        if (t < NPB) hist[t] = 0;
        __syncthreads();

        // stage + histogram
        for (int i = t; i < cnt; i += 512) {
            u64 p = srcbuf[cbase + i];
            stage[i] = p;
            atomicAdd(&hist[(int)(((u32)p >> 20) & (NPB - 1))], 1);
        }
        __syncthreads();

        // inclusive scan of 128 counters (hist[n] -> prefix through n)
        int orig = (t < NPB) ? hist[t] : 0;
        for (int d = 1; d < NPB; d <<= 1) {
            int tmp = (t >= d && t < NPB) ? hist[t - d] : 0;
            __syncthreads();
            if (t < NPB) hist[t] += tmp;
            __syncthreads();
        }
        if (t < NPB) cur[t] = hist[t] - orig;   // exclusive start
        __syncthreads();

        // scatter indices into node order
        for (int i = t; i < cnt; i += 512) {
            u64 p = stage[i];
            int local = (int)(((u32)p >> 20) & (NPB - 1));
            int pos = atomicAdd(&cur[local], 1);
            idx[pos] = (u16)i;
        }
        __syncthreads();

        // gather: nodes g0 and g0+64, 8 lanes each, 2-edge unroll
        #pragma unroll
        for (int half = 0; half < 2; ++half) {
            const int n = g0 + (half << 6);
            const int s0 = (n == 0) ? 0 : hist[n - 1];
            const int e0 = hist[n];
            float4 a = half ? acc1 : acc0;
            int j = s0;
            for (; j + 2 <= e0; j += 2) {
                const u64 p0 = stage[idx[j]];
                const u64 p1 = stage[idx[j + 1]];
                const float4 v0 = *(const float4*)&x[(((size_t)((u32)p0 & 0xFFFFFu)) << 5) + l4];
                const float4 v1 = *(const float4*)&x[(((size_t)((u32)p1 & 0xFFFFFu)) << 5) + l4];
                const float a0 = __uint_as_float((u32)(p0 >> 32));
                const float a1 = __uint_as_float((u32)(p1 >> 32));
                a.x = fmaf(a0, v0.x, a.x); a.y = fmaf(a0, v0.y, a.y);
                a.z = fmaf(a0, v0.z, a.z); a.w = fmaf(a0, v0.w, a.w);
                a.x = fmaf(a1, v1.x, a.x); a.y = fmaf(a1, v1.y, a.y);
                a.z = fmaf(a1, v1.z, a.z); a.w = fmaf(a1, v1.w, a.w);
            }
            if (j < e0) {
                const u64 p = stage[idx[j]];
                const float4 v = *(const float4*)&x[(((size_t)((u32)p & 0xFFFFFu)) << 5) + l4];
                const float av = __uint_as_float((u32)(p >> 32));
                a.x = fmaf(av, v.x, a.x); a.y = fmaf(av, v.y, a.y);
                a.z = fmaf(av, v.z, a.z); a.w = fmaf(av, v.w, a.w);
            }
            if (half) acc1 = a; else acc0 = a;
        }
    }

    // write out (each thread owns 4 floats of nodes g0 and g0+64)
    const int node0 = k << BSHIFT;
    const int n0 = node0 + g0;
    const int n1 = node0 + g0 + 64;
    if (n0 < N) *(float4*)&out[((size_t)n0 << 5) + l4] = acc0;
    if (n1 < N) *(float4*)&out[((size_t)n1 << 5) + l4] = acc1;
}

// ---------- fallback (generality): direct atomic scatter ----------
__global__ void fallback_scatter(const int* __restrict__ ei, const float* __restrict__ attr,
                                 const float* __restrict__ x, float* __restrict__ out, int E) {
    const long long total = (long long)E * D_FEAT;
    const long long stride = (long long)gridDim.x * blockDim.x;
    for (long long i = (long long)blockIdx.x * blockDim.x + threadIdx.x; i < total; i += stride) {
        const int e = (int)(i >> 5);
        const int d = (int)(i & 31);
        atomicAdd(&out[((long long)ei[e] << 5) + d],
                  attr[e] * x[((long long)ei[E + e] << 5) + d]);
    }
}

extern "C" void kernel_launch(void* const* d_in, const int* in_sizes, int n_in,
                              void* d_out, int out_size, void* d_ws, size_t ws_size,
                              hipStream_t stream) {
    const int* edge_index = (const int*)d_in[0];    // [2, E] int32
    const float* edge_attr = (const float*)d_in[1]; // [E] f32
    const float* x = (const float*)d_in[2];         // [N, 32] f32
    float* out = (float*)d_out;                     // [N, 32] f32

    const int E = in_sizes[1];
    const int N = in_sizes[2] / D_FEAT;
    const int NB = (N + NPB - 1) >> BSHIFT;

    // Workspace layout (256-B aligned sections)
    char* ws = (char*)d_ws;
    int* btot = (int*)ws;                                              // NB*PAD
    size_t o1 = (((size_t)NB * PAD * 4) + 255) & ~(size_t)255;
    int* bbase = (int*)(ws + o1);                                      // NB+1
    size_t o2 = (o1 + ((size_t)(NB + 1) * 4) + 255) & ~(size_t)255;
    int* rel = (int*)(ws + o2);                                        // NBLK*NB
    size_t o3 = (o2 + ((size_t)NBLK * NB * 4) + 255) & ~(size_t)255;
    u64* bufA = (u64*)(ws + o3);                                       // E
    size_t need = o3 + (size_t)E * 8;

    if (NB > NB_MAX || N > (1 << 20) || need > ws_size) {
        hipMemsetAsync(d_out, 0, (size_t)out_size * sizeof(float), stream);
        long long total = (long long)E * D_FEAT;
        int grid = (int)((total + 255) / 256);
        if (grid > 65536) grid = 65536;
        fallback_scatter<<<grid, 256, 0, stream>>>(edge_index, edge_attr, x, out, E);
        return;
    }

    hipMemsetAsync(btot, 0, (size_t)NB * PAD * 4, stream);

    const int epb = (E + NBLK - 1) / NBLK;

    count_reserve<<<NBLK, ABLK, 0, stream>>>(edge_index, btot, rel, E, NB, epb);
    scan_totals<<<1, NB_MAX, 0, stream>>>(btot, bbase, NB);
    bin_scatter<<<NBLK, ABLK, 0, stream>>>(edge_index, edge_attr, rel, bbase, bufA, E, NB, epb);
    sort_gather<<<NB, 512, 0, stream>>>(bufA, bbase, x, out, N);
}